// Round 21
// baseline (458.486 us; speedup 1.0000x reference)
//
#include <hip/hip_runtime.h>
#include <hip/hip_bf16.h>
#include <math.h>

#define BB 2
#define C0 96
#define LTOT 13824
#define DINC 192
#define L4S 3456
#define NCHUNK 432
#define CLEN 32

// Static device workspace (~368 MB .bss)
#define WS_FLOATS 92000000
__device__ __attribute__((aligned(256))) float g_ws[WS_FLOATS];

typedef __bf16 bf16x8 __attribute__((ext_vector_type(8)));
typedef short  s16x8  __attribute__((ext_vector_type(8)));
typedef short  s16x4  __attribute__((ext_vector_type(4)));
typedef float  f32x4  __attribute__((ext_vector_type(4)));

__device__ __forceinline__ f32x4 mfma16(s16x8 a, s16x8 b, f32x4 c){
  return __builtin_amdgcn_mfma_f32_16x16x32_bf16(
      __builtin_bit_cast(bf16x8, a), __builtin_bit_cast(bf16x8, b), c, 0, 0, 0);
}

__device__ __forceinline__ int sigma_idx(int dir, int p){
  if (dir == 0) return p;
  if (dir == 1) return LTOT - 1 - p;
  return 4*(p % L4S) + (p / L4S);
}

__device__ __forceinline__ float silu_f(float x){
  return x / (1.f + __expf(-x));
}

__device__ __forceinline__ float softplus_f(float x){
  return (x > 20.f) ? x : __logf(1.f + __expf(x));
}

__device__ __forceinline__ short bf16r(float x){
  return (short)__builtin_bit_cast(unsigned short, __float2bfloat16(x));
}

// pw[s] = e1^(s+1), log-depth multiply tree
__device__ __forceinline__ void pow_tree(float e1, float* pw){
  pw[0] = e1;
  pw[1] = e1*e1;
  pw[2] = pw[1]*e1;
  pw[3] = pw[1]*pw[1];
  pw[4] = pw[3]*e1;
  pw[5] = pw[3]*pw[1];
  pw[6] = pw[3]*pw[2];
  pw[7] = pw[3]*pw[3];
  pw[8] = pw[7]*e1;
  pw[9] = pw[7]*pw[1];
  pw[10]= pw[7]*pw[2];
  pw[11]= pw[7]*pw[3];
  pw[12]= pw[7]*pw[4];
  pw[13]= pw[7]*pw[5];
  pw[14]= pw[7]*pw[6];
  pw[15]= pw[7]*pw[7];
}

// ---------------- LayerNorm: x (B,96,L) -> xnorm (B,L,96) ----------------
__global__ __launch_bounds__(256) void k_ln(const float* __restrict__ x,
    const float* __restrict__ g, const float* __restrict__ bt, float* __restrict__ xn)
{
  int i = blockIdx.x*256 + threadIdx.x;
  if (i >= BB*LTOT) return;
  int b = i / LTOT, ll = i % LTOT;
  const float* xp = x + (size_t)b*C0*LTOT + ll;
  float s = 0.f, ss = 0.f;
  for (int c = 0; c < C0; ++c){ float v = xp[(size_t)c*LTOT]; s += v; ss += v*v; }
  float mu = s * (1.f/C0);
  float var = ss * (1.f/C0) - mu*mu;
  float inv = rsqrtf(var + 1e-5f);
  float* op = xn + (size_t)i*C0;
  for (int c = 0; c < C0; ++c){
    float v = xp[(size_t)c*LTOT];
    op[c] = (v - mu)*inv*g[c] + bt[c];
  }
}

// ---------------- in_proj MFMA: xnorm (B*L,96) @ W(384,96)^T -> xin | silu->gate ----------------
__global__ __launch_bounds__(256) void k_inproj(const float* __restrict__ xnorm,
    const float* __restrict__ W, float* __restrict__ xin, float* __restrict__ gate)
{
  __shared__ short Qs[256][40];
  __shared__ short Ws[96][40];
  int tid = threadIdx.x;
  long row0 = (long)blockIdx.x * 256;
  int y = blockIdx.y;
  int colb = (y & 1)*96;
  bool isGate = (y >= 2);
  const float* Wp = W + (long)y*96*96;
  int lane = tid & 63, wid = tid >> 6;
  int lr = lane & 15, lk = lane >> 4;
  f32x4 acc[4][6];
  #pragma unroll
  for (int i = 0; i < 4; ++i)
    #pragma unroll
    for (int j = 0; j < 6; ++j) acc[i][j] = f32x4{0.f,0.f,0.f,0.f};
  for (int kc = 0; kc < 3; ++kc){
    #pragma unroll
    for (int i = 0; i < 8; ++i){
      int flat4 = i*256 + tid;
      int row = flat4 >> 3, col4 = flat4 & 7;
      f32x4 a = *(const f32x4*)(xnorm + (row0 + row)*96 + kc*32 + col4*4);
      s16x4 o;
      #pragma unroll
      for (int e = 0; e < 4; ++e) o[e] = bf16r(a[e]);
      *(s16x4*)&Qs[row][col4*4] = o;
    }
    #pragma unroll
    for (int i = 0; i < 3; ++i){
      int flat4 = i*256 + tid;
      int row = flat4 >> 3, col4 = flat4 & 7;
      f32x4 wv = *(const f32x4*)(Wp + (long)row*96 + kc*32 + col4*4);
      s16x4 o;
      #pragma unroll
      for (int e = 0; e < 4; ++e) o[e] = bf16r(wv[e]);
      *(s16x4*)&Ws[row][col4*4] = o;
    }
    __syncthreads();
    #pragma unroll
    for (int rf = 0; rf < 4; ++rf){
      s16x8 af = *(const s16x8*)&Qs[wid*64 + rf*16 + lr][lk*8];
      #pragma unroll
      for (int cf = 0; cf < 6; ++cf){
        s16x8 wf = *(const s16x8*)&Ws[cf*16 + lr][lk*8];
        acc[rf][cf] = mfma16(wf, af, acc[rf][cf]);
      }
    }
    __syncthreads();
  }
  float* dst = isGate ? gate : xin;
  #pragma unroll
  for (int rf = 0; rf < 4; ++rf)
    #pragma unroll
    for (int cf = 0; cf < 6; ++cf){
      long l = row0 + wid*64 + rf*16 + lr;
      int n0 = cf*16 + lk*4;
      f32x4 v = acc[rf][cf];
      if (isGate){
        #pragma unroll
        for (int e = 0; e < 4; ++e) v[e] = silu_f(v[e]);
      }
      *(f32x4*)(dst + l*DINC + colb + n0) = v;
    }
}

// ---------------- xproj MFMA: u (3*B*L,192) @ W[dir](38,192)^T -> xdbl (stride 40) ----------------
__global__ __launch_bounds__(256) void k_xproj(const float* __restrict__ u,
    const float* __restrict__ W, float* __restrict__ xdbl)
{
  __shared__ short Qs[256][40];
  __shared__ short Ws[48][40];
  int tid = threadIdx.x;
  long row0 = (long)blockIdx.x * 256;
  int dir = (int)(row0 / 27648);
  const float* Wp = W + (long)dir*38*192;
  int lane = tid & 63, wid = tid >> 6;
  int lr = lane & 15, lk = lane >> 4;
  f32x4 acc[4][3];
  #pragma unroll
  for (int i = 0; i < 4; ++i)
    #pragma unroll
    for (int j = 0; j < 3; ++j) acc[i][j] = f32x4{0.f,0.f,0.f,0.f};
  for (int kc = 0; kc < 6; ++kc){
    #pragma unroll
    for (int i = 0; i < 8; ++i){
      int flat4 = i*256 + tid;
      int row = flat4 >> 3, col4 = flat4 & 7;
      f32x4 a = *(const f32x4*)(u + (row0 + row)*(long)DINC + kc*32 + col4*4);
      s16x4 o;
      #pragma unroll
      for (int e = 0; e < 4; ++e) o[e] = bf16r(a[e]);
      *(s16x4*)&Qs[row][col4*4] = o;
    }
    #pragma unroll
    for (int i = 0; i < 2; ++i){
      int flat4 = i*256 + tid;
      if (flat4 < 384){
        int row = flat4 >> 3, col4 = flat4 & 7;
        s16x4 o = {0,0,0,0};
        if (row < 38){
          f32x4 wv = *(const f32x4*)(Wp + (long)row*DINC + kc*32 + col4*4);
          #pragma unroll
          for (int e = 0; e < 4; ++e) o[e] = bf16r(wv[e]);
        }
        *(s16x4*)&Ws[row][col4*4] = o;
      }
    }
    __syncthreads();
    #pragma unroll
    for (int rf = 0; rf < 4; ++rf){
      s16x8 af = *(const s16x8*)&Qs[wid*64 + rf*16 + lr][lk*8];
      #pragma unroll
      for (int cf = 0; cf < 3; ++cf){
        s16x8 wf = *(const s16x8*)&Ws[cf*16 + lr][lk*8];
        acc[rf][cf] = mfma16(wf, af, acc[rf][cf]);
      }
    }
    __syncthreads();
  }
  #pragma unroll
  for (int rf = 0; rf < 4; ++rf)
    #pragma unroll
    for (int cf = 0; cf < 3; ++cf){
      long row = row0 + wid*64 + rf*16 + lr;
      int n0 = cf*16 + lk*4;
      if (n0 < 38)
        *(f32x4*)(xdbl + row*40 + n0) = acc[rf][cf];
    }
}

// ---------------- depthwise causal conv1d (permuted) + SiLU, f32x4 over d ----------------
__global__ __launch_bounds__(256) void k_dwconv(const float* __restrict__ xin,
    const float* __restrict__ cw, const float* __restrict__ cb, float* __restrict__ u)
{
  long i = (long)blockIdx.x*256 + threadIdx.x;
  if (i >= 3L*BB*LTOT*48) return;
  int dq = (int)(i % 48); long t = i / 48;
  int p = (int)(t % LTOT); t /= LTOT;
  int b = (int)(t % BB); int dir = (int)(t / BB);
  int d0 = dq*4;
  f32x4 acc = *(const f32x4*)(cb + dir*DINC + d0);
  const float* wbase = cw + ((long)dir*DINC + d0)*4;
  f32x4 w0 = *(const f32x4*)(wbase);
  f32x4 w1 = *(const f32x4*)(wbase + 4);
  f32x4 w2 = *(const f32x4*)(wbase + 8);
  f32x4 w3 = *(const f32x4*)(wbase + 12);
  #pragma unroll
  for (int kk = 0; kk < 4; ++kk){
    int pp = p - 3 + kk;
    if (pp >= 0){
      int l = sigma_idx(dir, pp);
      f32x4 xv = *(const f32x4*)(xin + ((long)b*LTOT + l)*DINC + d0);
      acc[0] += xv[0] * w0[kk];
      acc[1] += xv[1] * w1[kk];
      acc[2] += xv[2] * w2[kk];
      acc[3] += xv[3] * w3[kk];
    }
  }
  #pragma unroll
  for (int e = 0; e < 4; ++e) acc[e] = silu_f(acc[e]);
  *(f32x4*)(u + (((long)dir*BB + b)*LTOT + p)*DINC + d0) = acc;
}

__global__ __launch_bounds__(256) void k_prepA(const float* __restrict__ al, float* __restrict__ A){
  int i = blockIdx.x*256 + threadIdx.x;
  if (i < 3*DINC*16) A[i] = -__expf(al[i]);
}

// ---------------- scan phase 1: dual independent chunks per thread (ILP-2) ----------------
// grid 6*(NCHUNK/2) blocks; block handles chunks 2c, 2c+1 (CLEN=32 each)
__global__ __launch_bounds__(192) void k_scan1(const float* __restrict__ u,
    const float* __restrict__ dt_w, const float* __restrict__ dt_b,
    const float* __restrict__ xdbl,
    const float* __restrict__ Abuf, float* __restrict__ aprod, float* __restrict__ hend)
{
  int d = threadIdx.x;
  int c2 = blockIdx.x % (NCHUNK/2);
  int bd = blockIdx.x / (NCHUNK/2);
  int dir = bd >> 1;
  long pbase0 = (long)bd*LTOT + (long)(2*c2)*CLEN;
  long pbase1 = pbase0 + CLEN;
  float w6[6];
  #pragma unroll
  for (int i = 0; i < 6; ++i) w6[i] = dt_w[(dir*DINC + d)*6 + i];
  float bdt = dt_b[dir*DINC + d];
  const float* Ab = Abuf + ((long)dir*DINC + d)*16;
  float A0 = Ab[0];
  float h0[16], h1[16];
  #pragma unroll
  for (int s = 0; s < 16; ++s){ h0[s] = 0.f; h1[s] = 0.f; }
  bool fast = true;
  #pragma unroll
  for (int s = 1; s < 16; ++s)
    fast = fast && (fabsf(Ab[s] - (float)(s+1)*A0) <= 1e-4f*(float)(s+1));
  float sum0 = 0.f, sum1 = 0.f;
  if (fast){
    for (int j = 0; j < CLEN; ++j){
      const float* xr0 = xdbl + (pbase0 + j)*40;
      const float* xr1 = xdbl + (pbase1 + j)*40;
      float lu0 = u[(pbase0 + j)*DINC + d];
      float lu1 = u[(pbase1 + j)*DINC + d];
      float xv0 = bdt, xv1 = bdt;
      #pragma unroll
      for (int i = 0; i < 6; ++i){ xv0 += xr0[i]*w6[i]; xv1 += xr1[i]*w6[i]; }
      float ldt0 = softplus_f(xv0), ldt1 = softplus_f(xv1);
      sum0 += ldt0; sum1 += ldt1;
      float du0 = ldt0*lu0, du1 = ldt1*lu1;
      float pw0[16], pw1[16];
      pow_tree(__expf(ldt0*A0), pw0);
      pow_tree(__expf(ldt1*A0), pw1);
      #pragma unroll
      for (int s = 0; s < 16; ++s){
        h0[s] = pw0[s]*h0[s] + du0*xr0[6+s];
        h1[s] = pw1[s]*h1[s] + du1*xr1[6+s];
      }
    }
  } else {
    float A[16];
    #pragma unroll
    for (int s = 0; s < 16; ++s) A[s] = Ab[s];
    for (int j = 0; j < CLEN; ++j){
      const float* xr0 = xdbl + (pbase0 + j)*40;
      const float* xr1 = xdbl + (pbase1 + j)*40;
      float lu0 = u[(pbase0 + j)*DINC + d];
      float lu1 = u[(pbase1 + j)*DINC + d];
      float xv0 = bdt, xv1 = bdt;
      #pragma unroll
      for (int i = 0; i < 6; ++i){ xv0 += xr0[i]*w6[i]; xv1 += xr1[i]*w6[i]; }
      float ldt0 = softplus_f(xv0), ldt1 = softplus_f(xv1);
      sum0 += ldt0; sum1 += ldt1;
      float du0 = ldt0*lu0, du1 = ldt1*lu1;
      #pragma unroll
      for (int s = 0; s < 16; ++s){
        h0[s] = __expf(ldt0*A[s])*h0[s] + du0*xr0[6+s];
        h1[s] = __expf(ldt1*A[s])*h1[s] + du1*xr1[6+s];
      }
    }
  }
  long oi0 = (((long)bd*DINC + d)*NCHUNK + 2*c2)*16;
  long oi1 = oi0 + 16;
  if (fast){
    float pw0[16], pw1[16];
    pow_tree(__expf(A0*sum0), pw0);
    pow_tree(__expf(A0*sum1), pw1);
    #pragma unroll
    for (int s = 0; s < 16; ++s){
      aprod[oi0 + s] = pw0[s]; hend[oi0 + s] = h0[s];
      aprod[oi1 + s] = pw1[s]; hend[oi1 + s] = h1[s];
    }
  } else {
    #pragma unroll
    for (int s = 0; s < 16; ++s){
      aprod[oi0 + s] = __expf(Ab[s]*sum0); hend[oi0 + s] = h0[s];
      aprod[oi1 + s] = __expf(Ab[s]*sum1); hend[oi1 + s] = h1[s];
    }
  }
}

// ---------------- scan phase 2 ----------------
__global__ __launch_bounds__(256) void k_scan2(float* __restrict__ aprod, const float* __restrict__ hend){
  long i = (long)blockIdx.x*256 + threadIdx.x;
  if (i >= 6L*DINC*16) return;
  int s = (int)(i & 15); long t = i >> 4;
  int d = (int)(t % DINC); int bd = (int)(t / DINC);
  long base = (((long)bd*DINC + d)*NCHUNK)*16 + s;
  float H = 0.f;
  for (int c = 0; c < NCHUNK; ++c){
    long idx = base + (long)c*16;
    float a = aprod[idx], he = hend[idx];
    aprod[idx] = H;
    H = he + a*H;
  }
}

// ---------------- scan phase 3: dual independent chunks per thread (ILP-2) ----------------
__global__ __launch_bounds__(192) void k_scan3(const float* __restrict__ u,
    const float* __restrict__ dt_w, const float* __restrict__ dt_b,
    const float* __restrict__ xdbl,
    const float* __restrict__ Abuf, const float* __restrict__ hin,
    const float* __restrict__ Dp, const float* __restrict__ gate, float* __restrict__ qkv)
{
  int d = threadIdx.x;
  int c2 = blockIdx.x % (NCHUNK/2);
  int bd = blockIdx.x / (NCHUNK/2);
  int dir = bd >> 1, b = bd & 1;
  long pbase0 = (long)bd*LTOT + (long)(2*c2)*CLEN;
  long pbase1 = pbase0 + CLEN;
  float w6[6];
  #pragma unroll
  for (int i = 0; i < 6; ++i) w6[i] = dt_w[(dir*DINC + d)*6 + i];
  float bdt = dt_b[dir*DINC + d];
  const float* Ab = Abuf + ((long)dir*DINC + d)*16;
  float A0 = Ab[0];
  float h0[16], h1[16];
  long oi0 = (((long)bd*DINC + d)*NCHUNK + 2*c2)*16;
  long oi1 = oi0 + 16;
  #pragma unroll
  for (int s = 0; s < 16; ++s){
    h0[s] = hin[oi0 + s];
    h1[s] = hin[oi1 + s];
  }
  bool fast = true;
  #pragma unroll
  for (int s = 1; s < 16; ++s)
    fast = fast && (fabsf(Ab[s] - (float)(s+1)*A0) <= 1e-4f*(float)(s+1));
  float Dv = Dp[dir*DINC + d];
  if (fast){
    for (int j = 0; j < CLEN; ++j){
      const float* xr0 = xdbl + (pbase0 + j)*40;
      const float* xr1 = xdbl + (pbase1 + j)*40;
      float lu0 = u[(pbase0 + j)*DINC + d];
      float lu1 = u[(pbase1 + j)*DINC + d];
      float xv0 = bdt, xv1 = bdt;
      #pragma unroll
      for (int i = 0; i < 6; ++i){ xv0 += xr0[i]*w6[i]; xv1 += xr1[i]*w6[i]; }
      float ldt0 = softplus_f(xv0), ldt1 = softplus_f(xv1);
      float du0 = ldt0*lu0, du1 = ldt1*lu1;
      float pw0[16], pw1[16];
      pow_tree(__expf(ldt0*A0), pw0);
      pow_tree(__expf(ldt1*A0), pw1);
      float y0 = 0.f, y1 = 0.f;
      #pragma unroll
      for (int s = 0; s < 16; ++s){
        h0[s] = pw0[s]*h0[s] + du0*xr0[6+s];
        y0 += h0[s]*xr0[22+s];
        h1[s] = pw1[s]*h1[s] + du1*xr1[6+s];
        y1 += h1[s]*xr1[22+s];
      }
      int pl0 = (2*c2)*CLEN + j;
      int pl1 = pl0 + CLEN;
      int l0 = sigma_idx(dir, pl0);
      int l1 = sigma_idx(dir, pl1);
      long li0 = (long)b*LTOT + l0;
      long li1 = (long)b*LTOT + l1;
      qkv[(((long)dir*BB + b)*LTOT + l0)*DINC + d] = (y0 + lu0*Dv) * gate[li0*DINC + d];
      qkv[(((long)dir*BB + b)*LTOT + l1)*DINC + d] = (y1 + lu1*Dv) * gate[li1*DINC + d];
    }
  } else {
    float A[16];
    #pragma unroll
    for (int s = 0; s < 16; ++s) A[s] = Ab[s];
    for (int j = 0; j < CLEN; ++j){
      const float* xr0 = xdbl + (pbase0 + j)*40;
      const float* xr1 = xdbl + (pbase1 + j)*40;
      float lu0 = u[(pbase0 + j)*DINC + d];
      float lu1 = u[(pbase1 + j)*DINC + d];
      float xv0 = bdt, xv1 = bdt;
      #pragma unroll
      for (int i = 0; i < 6; ++i){ xv0 += xr0[i]*w6[i]; xv1 += xr1[i]*w6[i]; }
      float ldt0 = softplus_f(xv0), ldt1 = softplus_f(xv1);
      float du0 = ldt0*lu0, du1 = ldt1*lu1;
      float y0 = 0.f, y1 = 0.f;
      #pragma unroll
      for (int s = 0; s < 16; ++s){
        h0[s] = __expf(ldt0*A[s])*h0[s] + du0*xr0[6+s];
        y0 += h0[s]*xr0[22+s];
        h1[s] = __expf(ldt1*A[s])*h1[s] + du1*xr1[6+s];
        y1 += h1[s]*xr1[22+s];
      }
      int pl0 = (2*c2)*CLEN + j;
      int pl1 = pl0 + CLEN;
      int l0 = sigma_idx(dir, pl0);
      int l1 = sigma_idx(dir, pl1);
      long li0 = (long)b*LTOT + l0;
      long li1 = (long)b*LTOT + l1;
      qkv[(((long)dir*BB + b)*LTOT + l0)*DINC + d] = (y0 + lu0*Dv) * gate[li0*DINC + d];
      qkv[(((long)dir*BB + b)*LTOT + l1)*DINC + d] = (y1 + lu1*Dv) * gate[li1*DINC + d];
    }
  }
}

// ---------------- QK^T via MFMA: partials per (lc,et,dtl,b) block ----------------
__global__ __launch_bounds__(256) void k_qkm(const float* __restrict__ q,
    const float* __restrict__ kkv, float* __restrict__ pb)
{
  __shared__ short Qst[64][36];
  __shared__ short Kst[64][36];
  int tid = threadIdx.x;
  int bx = blockIdx.x;
  int lc = bx % 24; int et = (bx/24) % 3; int dtl = (bx/72) % 3; int b = bx/216;
  long base = (long)b*LTOT + (long)lc*576;
  int lane = tid & 63, wid = tid >> 6;
  int lr = lane & 15, lk = lane >> 4;
  f32x4 acc[4];
  #pragma unroll
  for (int i = 0; i < 4; ++i) acc[i] = f32x4{0.f,0.f,0.f,0.f};
  for (int sc = 0; sc < 18; ++sc){
    int l0 = sc*32;
    #pragma unroll
    for (int i = 0; i < 2; ++i){
      int flat4 = i*256 + tid;
      int l = flat4 >> 4, dq = flat4 & 15;
      int d0 = dq*4;
      f32x4 qv = *(const f32x4*)(q   + (base + l0 + l)*(long)DINC + dtl*64 + d0);
      f32x4 kv = *(const f32x4*)(kkv + (base + l0 + l)*(long)DINC + et *64 + d0);
      #pragma unroll
      for (int e = 0; e < 4; ++e){
        Qst[d0+e][l] = bf16r(qv[e]);
        Kst[d0+e][l] = bf16r(kv[e]);
      }
    }
    __syncthreads();
    s16x8 kf = *(const s16x8*)&Kst[wid*16 + lr][lk*8];
    #pragma unroll
    for (int rf = 0; rf < 4; ++rf){
      s16x8 qf = *(const s16x8*)&Qst[rf*16 + lr][lk*8];
      acc[rf] = mfma16(qf, kf, acc[rf]);
    }
    __syncthreads();
  }
  float* pbb = pb + (long)bx*4096;
  #pragma unroll
  for (int rf = 0; rf < 4; ++rf)
    #pragma unroll
    for (int e = 0; e < 4; ++e)
      pbb[(rf*16 + lk*4 + e)*64 + wid*16 + lr] = acc[rf][e];
}

// ---------------- reduce qk partials over lc -> attn ----------------
__global__ __launch_bounds__(256) void k_qred(const float* __restrict__ pb,
    float* __restrict__ attn)
{
  int i4 = blockIdx.x*256 + threadIdx.x;
  if (i4 >= 18432) return;
  int i = i4*4;
  int b = i / 36864; int r = i % 36864;
  int dg = r / 192, eg = r % 192;
  int dtl = dg / 64, d = dg % 64;
  int et = eg / 64, e0 = eg % 64;
  long pbase = ((long)(24*et + 72*dtl + 216*b))*4096 + d*64 + e0;
  f32x4 s = {0.f,0.f,0.f,0.f};
  for (int lc = 0; lc < 24; ++lc){
    f32x4 v = *(const f32x4*)(pb + pbase + (long)lc*4096);
    #pragma unroll
    for (int e = 0; e < 4; ++e) s[e] += v[e];
  }
  *(f32x4*)(attn + i) = s;
}

__global__ __launch_bounds__(64) void k_softmax(float* __restrict__ attn){
  int row = blockIdx.x, tid = threadIdx.x;
  float* p = attn + (long)row*DINC;
  float v0 = p[tid], v1 = p[tid+64], v2 = p[tid+128];
  float m = fmaxf(v0, fmaxf(v1, v2));
  #pragma unroll
  for (int off = 32; off >= 1; off >>= 1) m = fmaxf(m, __shfl_xor(m, off));
  float e0 = __expf(v0-m), e1 = __expf(v1-m), e2 = __expf(v2-m);
  float s = e0 + e1 + e2;
  #pragma unroll
  for (int off = 32; off >= 1; off >>= 1) s += __shfl_xor(s, off);
  float inv = 1.f/s;
  p[tid] = e0*inv; p[tid+64] = e1*inv; p[tid+128] = e2*inv;
}

// ---------------- out_a = v @ attn^T fused with view-transpose -> inT1 bf16 ----------------
__global__ __launch_bounds__(256) void k_outa(const float* __restrict__ v,
    const float* __restrict__ attn, __hip_bfloat16* __restrict__ inT1)
{
  __shared__ short Vs[192][40];
  __shared__ short Ws[192][40];
  int tid = threadIdx.x;
  int r0 = blockIdx.x;
  int b  = blockIdx.y;
  int lane = tid & 63, wid = tid >> 6;
  int lr = lane & 15, lk = lane >> 4;
  const float* vb = v + (long)b*LTOT*DINC;
  const float* ab = attn + (long)b*DINC*DINC;
  f32x4 acc[3][12];
  #pragma unroll
  for (int i = 0; i < 3; ++i)
    #pragma unroll
    for (int j = 0; j < 12; ++j) acc[i][j] = f32x4{0.f,0.f,0.f,0.f};
  for (int kc = 0; kc < 6; ++kc){
    #pragma unroll
    for (int i = 0; i < 6; ++i){
      int flat4 = i*256 + tid;
      int row = flat4 >> 3, col4 = flat4 & 7;
      int l = r0 + 72*row;
      f32x4 vv = *(const f32x4*)(vb + (long)l*DINC + kc*32 + col4*4);
      f32x4 aa = *(const f32x4*)(ab + (long)row*DINC + kc*32 + col4*4);
      s16x4 vs, as;
      #pragma unroll
      for (int e = 0; e < 4; ++e){ vs[e] = bf16r(vv[e]); as[e] = bf16r(aa[e]); }
      *(s16x4*)&Vs[row][col4*4] = vs;
      *(s16x4*)&Ws[row][col4*4] = as;
    }
    __syncthreads();
    #pragma unroll
    for (int cf = 0; cf < 12; ++cf){
      s16x8 wf = *(const s16x8*)&Ws[cf*16 + lr][lk*8];
      #pragma unroll
      for (int c = 0; c < 3; ++c){
        s16x8 af = *(const s16x8*)&Vs[wid*48 + c*16 + lr][lk*8];
        acc[c][cf] = mfma16(af, wf, acc[c][cf]);
      }
    }
    __syncthreads();
  }
  #pragma unroll
  for (int c = 0; c < 3; ++c)
    #pragma unroll
    for (int cf = 0; cf < 12; ++cf){
      int ch0 = wid*48 + c*16 + lk*4;
      int d = cf*16 + lr;
      s16x4 o;
      #pragma unroll
      for (int e = 0; e < 4; ++e) o[e] = bf16r(acc[c][cf][e]);
      *(s16x4*)(inT1 + ((long)(b*13824 + 192*r0 + d))*192 + ch0) = o;
    }
}

// ---------------- out_m = (q+k+v) @ out_proj^T -> bf16 inT2[.][96..192) ----------------
__global__ __launch_bounds__(256) void k_outm(const float* __restrict__ qkv,
    const float* __restrict__ Wo, __hip_bfloat16* __restrict__ inT2)
{
  __shared__ short Qs[256][40];
  __shared__ short Ws[96][40];
  int tid = threadIdx.x;
  long row0 = (long)blockIdx.x * 256;
  int lane = tid & 63, wid = tid >> 6;
  int lr = lane & 15, lk = lane >> 4;
  const size_t S = (size_t)BB*LTOT*DINC;
  f32x4 acc[4][6];
  #pragma unroll
  for (int i = 0; i < 4; ++i)
    #pragma unroll
    for (int j = 0; j < 6; ++j) acc[i][j] = f32x4{0.f,0.f,0.f,0.f};
  for (int kc = 0; kc < 6; ++kc){
    #pragma unroll
    for (int i = 0; i < 8; ++i){
      int flat4 = i*256 + tid;
      int row = flat4 >> 3, col4 = flat4 & 7;
      long base = (row0 + row)*(long)DINC + kc*32 + col4*4;
      f32x4 a0 = *(const f32x4*)(qkv + base);
      f32x4 a1 = *(const f32x4*)(qkv + S + base);
      f32x4 a2 = *(const f32x4*)(qkv + 2*S + base);
      s16x4 o;
      #pragma unroll
      for (int e = 0; e < 4; ++e) o[e] = bf16r(a0[e] + a1[e] + a2[e]);
      *(s16x4*)&Qs[row][col4*4] = o;
    }
    #pragma unroll
    for (int i = 0; i < 3; ++i){
      int flat4 = i*256 + tid;
      int row = flat4 >> 3, col4 = flat4 & 7;
      f32x4 wv = *(const f32x4*)(Wo + (long)row*DINC + kc*32 + col4*4);
      s16x4 o;
      #pragma unroll
      for (int e = 0; e < 4; ++e) o[e] = bf16r(wv[e]);
      *(s16x4*)&Ws[row][col4*4] = o;
    }
    __syncthreads();
    #pragma unroll
    for (int rf = 0; rf < 4; ++rf){
      s16x8 af = *(const s16x8*)&Qs[wid*64 + rf*16 + lr][lk*8];
      #pragma unroll
      for (int cf = 0; cf < 6; ++cf){
        s16x8 wf = *(const s16x8*)&Ws[cf*16 + lr][lk*8];
        acc[rf][cf] = mfma16(wf, af, acc[rf][cf]);
      }
    }
    __syncthreads();
  }
  #pragma unroll
  for (int rf = 0; rf < 4; ++rf)
    #pragma unroll
    for (int cf = 0; cf < 6; ++cf){
      long row = row0 + wid*64 + rf*16 + lr;
      int n0 = cf*16 + lk*4;
      s16x4 o;
      #pragma unroll
      for (int e = 0; e < 4; ++e) o[e] = bf16r(acc[rf][cf][e]);
      *(s16x4*)(inT2 + row*192 + 96 + n0) = o;
    }
}

// ---------------- pack conv weights (96,192,27) f32 -> bf16 [tap][kc][oc][icl] ----------------
__global__ __launch_bounds__(256) void k_pack(const float* __restrict__ w1,
    const float* __restrict__ w2, __hip_bfloat16* __restrict__ p1, __hip_bfloat16* __restrict__ p2)
{
  int i = blockIdx.x*256 + threadIdx.x;
  if (i >= 2*497664) return;
  int which = i / 497664; int r = i % 497664;
  int icl = r & 31; int oc = (r >> 5) % 96; int kc = (r / 3072) % 6; int t = r / 18432;
  const float* w = which ? w2 : w1;
  float v = w[(long)oc*5184 + (kc*32 + icl)*27 + t];
  (which ? p2 : p1)[r] = __float2bfloat16(v);
}

// ---------------- conv3d via LDS-staged dbuf implicit GEMM, sp-tile 64 ----------------
template<int CONV>
__global__ __launch_bounds__(128, 2) void k_convm(const __hip_bfloat16* __restrict__ inT,
    const __hip_bfloat16* __restrict__ Wp, float* __restrict__ pbuf)
{
  __shared__ short As[2][64][32];
  __shared__ short Ws[2][96][32];
  int tid = threadIdx.x;
  int bx = blockIdx.x;
  int g = bx / 432; int rem = bx % 432; int b = rem / 216; int tile = rem % 216;
  int sp0 = tile * 64;
  int kd = g - 1;
  int lane = tid & 63, wid = tid >> 6;
  int lr = lane & 15, lk = lane >> 4;
  const s16x8 zer = {0,0,0,0,0,0,0,0};

  int chnk = tid & 3;
  int hh[2], wwv[2], zzv[2], spv[2];
  #pragma unroll
  for (int k = 0; k < 2; ++k){
    int sp = sp0 + (tid >> 2) + 32*k;
    spv[k] = sp; hh[k] = sp/576; wwv[k] = (sp/24)%24; zzv[k] = sp%24;
  }

  f32x4 acc[6][2];
  #pragma unroll
  for (int i = 0; i < 6; ++i)
    #pragma unroll
    for (int j = 0; j < 2; ++j) acc[i][j] = f32x4{0.f,0.f,0.f,0.f};

  s16x8 av[2], wv[3];
  {
    int dw = -1, dz = -1;
    #pragma unroll
    for (int k = 0; k < 2; ++k){
      av[k] = zer;
      bool ok = ((unsigned)(hh[k]+kd) < 24u) && ((unsigned)(wwv[k]+dw) < 24u) && ((unsigned)(zzv[k]+dz) < 24u);
      if (ok){
        int spp = spv[k] + kd*576 + dw*24 + dz;
        av[k] = *(const s16x8*)(inT + ((long)(b*13824 + spp))*192 + chnk*8);
      }
    }
    long wb = ((long)(g*9)*6)*3072;
    #pragma unroll
    for (int k = 0; k < 3; ++k)
      wv[k] = *(const s16x8*)(Wp + wb + (long)(tid + 128*k)*8);
  }
  #pragma unroll
  for (int k = 0; k < 2; ++k)
    *(s16x8*)&As[0][(tid>>2) + 32*k][chnk*8] = av[k];
  #pragma unroll
  for (int k = 0; k < 3; ++k)
    *(s16x8*)&Ws[0][(tid + 128*k) >> 2][chnk*8] = wv[k];
  __syncthreads();

  for (int s = 0; s < 54; ++s){
    int buf = s & 1;
    int sn = s + 1;
    if (sn < 54){
      int t = sn / 6, kc = sn - 6*t;
      int td3 = t / 3;
      int dw = td3 - 1, dz = t - 3*td3 - 1;
      #pragma unroll
      for (int k = 0; k < 2; ++k){
        av[k] = zer;
        bool ok = ((unsigned)(hh[k]+kd) < 24u) && ((unsigned)(wwv[k]+dw) < 24u) && ((unsigned)(zzv[k]+dz) < 24u);
        if (ok){
          int spp = spv[k] + kd*576 + dw*24 + dz;
          av[k] = *(const s16x8*)(inT + ((long)(b*13824 + spp))*192 + kc*32 + chnk*8);
        }
      }
      long wb = ((long)(g*9 + t)*6 + kc)*3072;
      #pragma unroll
      for (int k = 0; k < 3; ++k)
        wv[k] = *(const s16x8*)(Wp + wb + (long)(tid + 128*k)*8);
    }
    s16x8 bfr[2];
    #pragma unroll
    for (int c = 0; c < 2; ++c)
      bfr[c] = *(const s16x8*)&As[buf][wid*32 + c*16 + lr][lk*8];
    #pragma unroll
    for (int cf = 0; cf < 6; ++cf){
      s16x8 wf = *(const s16x8*)&Ws[buf][cf*16 + lr][lk*8];
      #pragma unroll
      for (int c = 0; c < 2; ++c){
        if (CONV == 1) acc[cf][c] = mfma16(wf, bfr[c], acc[cf][c]);
        else           acc[cf][c] = mfma16(bfr[c], wf, acc[cf][c]);
      }
    }
    if (sn < 54){
      #pragma unroll
      for (int k = 0; k < 2; ++k)
        *(s16x8*)&As[buf^1][(tid>>2) + 32*k][chnk*8] = av[k];
      #pragma unroll
      for (int k = 0; k < 3; ++k)
        *(s16x8*)&Ws[buf^1][(tid + 128*k) >> 2][chnk*8] = wv[k];
    }
    __syncthreads();
  }

  long gb = (long)(g*2 + b);
  #pragma unroll
  for (int cf = 0; cf < 6; ++cf)
    #pragma unroll
    for (int c = 0; c < 2; ++c){
      if (CONV == 1){
        int sp = sp0 + wid*32 + c*16 + lr;
        int oc0 = cf*16 + lk*4;
        *reinterpret_cast<f32x4*>(pbuf + (gb*13824 + sp)*96 + oc0) = acc[cf][c];
      } else {
        int oc = cf*16 + lr;
        int spr = sp0 + wid*32 + c*16 + lk*4;
        *reinterpret_cast<f32x4*>(pbuf + (gb*96 + oc)*13824 + spr) = acc[cf][c];
      }
    }
}

// ---------------- reduce conv1 partials + bias -> bf16 inT2[.][0..96), f32x4 ----------------
__global__ __launch_bounds__(256) void k_red1(const float* __restrict__ pbuf,
    const float* __restrict__ bias, __hip_bfloat16* __restrict__ inT2)
{
  int i4 = blockIdx.x*256 + threadIdx.x;
  if (i4 >= 663552) return;
  int i = i4*4;
  int oc0 = i % 96;
  long row = i / 96;
  f32x4 v0 = *(const f32x4*)(pbuf + i);
  f32x4 v1 = *(const f32x4*)(pbuf + 2654208 + i);
  f32x4 v2 = *(const f32x4*)(pbuf + 2*2654208 + i);
  f32x4 bv = *(const f32x4*)(bias + oc0);
  s16x4 o;
  #pragma unroll
  for (int e = 0; e < 4; ++e) o[e] = bf16r(v0[e] + v1[e] + v2[e] + bv[e]);
  *(s16x4*)(inT2 + row*192 + oc0) = o;
}

// ---------------- reduce conv2 partials + bias + x -> d_out, f32x4 ----------------
__global__ __launch_bounds__(256) void k_red2(const float* __restrict__ pbuf,
    const float* __restrict__ bias, const float* __restrict__ x, float* __restrict__ out)
{
  int i4 = blockIdx.x*256 + threadIdx.x;
  if (i4 >= 663552) return;
  int i = i4*4;
  int oc = (i / 13824) % 96;
  f32x4 v0 = *(const f32x4*)(pbuf + i);
  f32x4 v1 = *(const f32x4*)(pbuf + 2654208 + i);
  f32x4 v2 = *(const f32x4*)(pbuf + 2*2654208 + i);
  f32x4 xv = *(const f32x4*)(x + i);
  f32x4 o;
  float bv = bias[oc];
  #pragma unroll
  for (int e = 0; e < 4; ++e) o[e] = v0[e] + v1[e] + v2[e] + bv + xv[e];
  *(f32x4*)(out + i) = o;
}

extern "C" void kernel_launch(void* const* d_in, const int* in_sizes, int n_in,
                              void* d_out, int out_size, void* d_ws, size_t ws_size,
                              hipStream_t stream)
{
  const float* x          = (const float*)d_in[0];
  const float* ln_g       = (const float*)d_in[1];
  const float* ln_b       = (const float*)d_in[2];
  const float* in_proj_w  = (const float*)d_in[3];
  const float* conv_w     = (const float*)d_in[4];
  const float* conv_b     = (const float*)d_in[5];
  const float* xproj_w    = (const float*)d_in[6];
  const float* dt_w       = (const float*)d_in[7];
  const float* dt_b       = (const float*)d_in[8];
  const float* A_log      = (const float*)d_in[9];
  const float* Dp         = (const float*)d_in[10];
  const float* out_proj_w = (const float*)d_in[11];
  const float* f1_w       = (const float*)d_in[12];
  const float* f1_b       = (const float*)d_in[13];
  const float* f2_w       = (const float*)d_in[14];
  const float* f2_b       = (const float*)d_in[15];
  float* out = (float*)d_out;

  const size_t BL = (size_t)BB*LTOT;
  const size_t S  = BL*DINC;

  void* wsp = nullptr;
  (void)hipGetSymbolAddress(&wsp, HIP_SYMBOL(g_ws));
  float* ws = (float*)wsp;
  size_t off = 0;
  auto alloc = [&](size_t n){ float* p = ws + off; off += n; return p; };
  float* xnorm = alloc(BL*C0);
  float* xin   = alloc(S);
  float* gate  = alloc(S);
  float* u     = alloc(3*S);
  float* xdbl  = alloc(3*BL*40);
  float* qkv   = alloc(3*S);
  float* Abuf  = alloc(3*DINC*16);
  float* aprod = alloc((size_t)6*DINC*16*NCHUNK);
  float* hend  = alloc((size_t)6*DINC*16*NCHUNK);
  float* attn  = alloc((size_t)BB*DINC*DINC);
  float* pbuf  = alloc((size_t)3*2654208);
  __hip_bfloat16* inT1 = (__hip_bfloat16*)alloc(2654208);
  __hip_bfloat16* inT2 = (__hip_bfloat16*)alloc(2654208);
  __hip_bfloat16* Wp1  = (__hip_bfloat16*)alloc(248832);
  __hip_bfloat16* Wp2  = (__hip_bfloat16*)alloc(248832);

  // 0) pack conv weights to bf16
  k_pack<<<3888, 256, 0, stream>>>(f1_w, f2_w, Wp1, Wp2);
  // 1) layernorm + transpose
  k_ln<<<108, 256, 0, stream>>>(x, ln_g, ln_b, xnorm);
  // 2) in_proj MFMA -> xin + silu gate
  k_inproj<<<dim3(108, 4), 256, 0, stream>>>(xnorm, in_proj_w, xin, gate);
  // 3) depthwise causal conv + silu
  k_dwconv<<<15552, 256, 0, stream>>>(xin, conv_w, conv_b, u);
  // 4) xproj MFMA -> xdbl (stride 40)
  k_xproj<<<324, 256, 0, stream>>>(u, xproj_w, xdbl);
  // 5) A = -exp(A_log)
  k_prepA<<<36, 256, 0, stream>>>(A_log, Abuf);
  // 6) chunked selective scan (dual chains/thread, NCHUNK=432/CLEN=32)
  k_scan1<<<6*(NCHUNK/2), 192, 0, stream>>>(u, dt_w, dt_b, xdbl, Abuf, aprod, hend);
  k_scan2<<<72, 256, 0, stream>>>(aprod, hend);
  k_scan3<<<6*(NCHUNK/2), 192, 0, stream>>>(u, dt_w, dt_b, xdbl, Abuf, aprod, Dp, gate, qkv);
  // 7) attention matrix (MFMA + partial reduce) + softmax
  k_qkm<<<432, 256, 0, stream>>>(qkv, qkv + S, pbuf);
  k_qred<<<72, 256, 0, stream>>>(pbuf, attn);
  k_softmax<<<BB*DINC, 64, 0, stream>>>(attn);
  // 8) out_a MFMA + fused transpose -> inT1 bf16
  k_outa<<<dim3(72, 2), 256, 0, stream>>>(qkv + 2*S, attn, inT1);
  // 9) out_m MFMA -> bf16 inT2[.][96..192)
  k_outm<<<108, 256, 0, stream>>>(qkv, out_proj_w, inT2);
  // 10) conv3d #1 (sp-tile 64, grid 1296) + reduce -> inT2[.][0..96)
  k_convm<1><<<1296, 128, 0, stream>>>(inT1, Wp1, pbuf);
  k_red1<<<2592, 256, 0, stream>>>(pbuf, f1_b, inT2);
  // 11) conv3d #2 + reduce + bias + x -> d_out
  k_convm<2><<<1296, 128, 0, stream>>>(inT2, Wp2, pbuf);
  k_red2<<<2592, 256, 0, stream>>>(pbuf, f2_b, x, out);
}

// Round 22
// 411.706 us; speedup vs baseline: 1.1136x; 1.1136x over previous
//
#include <hip/hip_runtime.h>
#include <hip/hip_bf16.h>
#include <math.h>

#define BB 2
#define C0 96
#define LTOT 13824
#define DINC 192
#define L4S 3456
#define NCHUNK 216
#define CLEN 64

// Static device workspace (~368 MB .bss)
#define WS_FLOATS 92000000
__device__ __attribute__((aligned(256))) float g_ws[WS_FLOATS];

typedef __bf16 bf16x8 __attribute__((ext_vector_type(8)));
typedef short  s16x8  __attribute__((ext_vector_type(8)));
typedef short  s16x4  __attribute__((ext_vector_type(4)));
typedef float  f32x4  __attribute__((ext_vector_type(4)));

__device__ __forceinline__ f32x4 mfma16(s16x8 a, s16x8 b, f32x4 c){
  return __builtin_amdgcn_mfma_f32_16x16x32_bf16(
      __builtin_bit_cast(bf16x8, a), __builtin_bit_cast(bf16x8, b), c, 0, 0, 0);
}

__device__ __forceinline__ int sigma_idx(int dir, int p){
  if (dir == 0) return p;
  if (dir == 1) return LTOT - 1 - p;
  return 4*(p % L4S) + (p / L4S);
}

__device__ __forceinline__ float silu_f(float x){
  return x / (1.f + __expf(-x));
}

__device__ __forceinline__ float softplus_f(float x){
  return (x > 20.f) ? x : __logf(1.f + __expf(x));
}

__device__ __forceinline__ short bf16r(float x){
  return (short)__builtin_bit_cast(unsigned short, __float2bfloat16(x));
}

// pw[s] = e1^(s+1), log-depth multiply tree
__device__ __forceinline__ void pow_tree(float e1, float* pw){
  pw[0] = e1;
  pw[1] = e1*e1;
  pw[2] = pw[1]*e1;
  pw[3] = pw[1]*pw[1];
  pw[4] = pw[3]*e1;
  pw[5] = pw[3]*pw[1];
  pw[6] = pw[3]*pw[2];
  pw[7] = pw[3]*pw[3];
  pw[8] = pw[7]*e1;
  pw[9] = pw[7]*pw[1];
  pw[10]= pw[7]*pw[2];
  pw[11]= pw[7]*pw[3];
  pw[12]= pw[7]*pw[4];
  pw[13]= pw[7]*pw[5];
  pw[14]= pw[7]*pw[6];
  pw[15]= pw[7]*pw[7];
}

// ---------------- LayerNorm: x (B,96,L) -> xnorm (B,L,96) ----------------
__global__ __launch_bounds__(256) void k_ln(const float* __restrict__ x,
    const float* __restrict__ g, const float* __restrict__ bt, float* __restrict__ xn)
{
  int i = blockIdx.x*256 + threadIdx.x;
  if (i >= BB*LTOT) return;
  int b = i / LTOT, ll = i % LTOT;
  const float* xp = x + (size_t)b*C0*LTOT + ll;
  float s = 0.f, ss = 0.f;
  for (int c = 0; c < C0; ++c){ float v = xp[(size_t)c*LTOT]; s += v; ss += v*v; }
  float mu = s * (1.f/C0);
  float var = ss * (1.f/C0) - mu*mu;
  float inv = rsqrtf(var + 1e-5f);
  float* op = xn + (size_t)i*C0;
  for (int c = 0; c < C0; ++c){
    float v = xp[(size_t)c*LTOT];
    op[c] = (v - mu)*inv*g[c] + bt[c];
  }
}

// ---------------- in_proj MFMA: xnorm (B*L,96) @ W(384,96)^T -> xin | silu->gate ----------------
__global__ __launch_bounds__(256) void k_inproj(const float* __restrict__ xnorm,
    const float* __restrict__ W, float* __restrict__ xin, float* __restrict__ gate)
{
  __shared__ short Qs[256][40];
  __shared__ short Ws[96][40];
  int tid = threadIdx.x;
  long row0 = (long)blockIdx.x * 256;
  int y = blockIdx.y;
  int colb = (y & 1)*96;
  bool isGate = (y >= 2);
  const float* Wp = W + (long)y*96*96;
  int lane = tid & 63, wid = tid >> 6;
  int lr = lane & 15, lk = lane >> 4;
  f32x4 acc[4][6];
  #pragma unroll
  for (int i = 0; i < 4; ++i)
    #pragma unroll
    for (int j = 0; j < 6; ++j) acc[i][j] = f32x4{0.f,0.f,0.f,0.f};
  for (int kc = 0; kc < 3; ++kc){
    #pragma unroll
    for (int i = 0; i < 8; ++i){
      int flat4 = i*256 + tid;
      int row = flat4 >> 3, col4 = flat4 & 7;
      f32x4 a = *(const f32x4*)(xnorm + (row0 + row)*96 + kc*32 + col4*4);
      s16x4 o;
      #pragma unroll
      for (int e = 0; e < 4; ++e) o[e] = bf16r(a[e]);
      *(s16x4*)&Qs[row][col4*4] = o;
    }
    #pragma unroll
    for (int i = 0; i < 3; ++i){
      int flat4 = i*256 + tid;
      int row = flat4 >> 3, col4 = flat4 & 7;
      f32x4 wv = *(const f32x4*)(Wp + (long)row*96 + kc*32 + col4*4);
      s16x4 o;
      #pragma unroll
      for (int e = 0; e < 4; ++e) o[e] = bf16r(wv[e]);
      *(s16x4*)&Ws[row][col4*4] = o;
    }
    __syncthreads();
    #pragma unroll
    for (int rf = 0; rf < 4; ++rf){
      s16x8 af = *(const s16x8*)&Qs[wid*64 + rf*16 + lr][lk*8];
      #pragma unroll
      for (int cf = 0; cf < 6; ++cf){
        s16x8 wf = *(const s16x8*)&Ws[cf*16 + lr][lk*8];
        acc[rf][cf] = mfma16(wf, af, acc[rf][cf]);
      }
    }
    __syncthreads();
  }
  float* dst = isGate ? gate : xin;
  #pragma unroll
  for (int rf = 0; rf < 4; ++rf)
    #pragma unroll
    for (int cf = 0; cf < 6; ++cf){
      long l = row0 + wid*64 + rf*16 + lr;
      int n0 = cf*16 + lk*4;
      f32x4 v = acc[rf][cf];
      if (isGate){
        #pragma unroll
        for (int e = 0; e < 4; ++e) v[e] = silu_f(v[e]);
      }
      *(f32x4*)(dst + l*DINC + colb + n0) = v;
    }
}

// ---------------- xproj MFMA: u (3*B*L,192) @ W[dir](38,192)^T -> xdbl (stride 40) ----------------
__global__ __launch_bounds__(256) void k_xproj(const float* __restrict__ u,
    const float* __restrict__ W, float* __restrict__ xdbl)
{
  __shared__ short Qs[256][40];
  __shared__ short Ws[48][40];
  int tid = threadIdx.x;
  long row0 = (long)blockIdx.x * 256;
  int dir = (int)(row0 / 27648);
  const float* Wp = W + (long)dir*38*192;
  int lane = tid & 63, wid = tid >> 6;
  int lr = lane & 15, lk = lane >> 4;
  f32x4 acc[4][3];
  #pragma unroll
  for (int i = 0; i < 4; ++i)
    #pragma unroll
    for (int j = 0; j < 3; ++j) acc[i][j] = f32x4{0.f,0.f,0.f,0.f};
  for (int kc = 0; kc < 6; ++kc){
    #pragma unroll
    for (int i = 0; i < 8; ++i){
      int flat4 = i*256 + tid;
      int row = flat4 >> 3, col4 = flat4 & 7;
      f32x4 a = *(const f32x4*)(u + (row0 + row)*(long)DINC + kc*32 + col4*4);
      s16x4 o;
      #pragma unroll
      for (int e = 0; e < 4; ++e) o[e] = bf16r(a[e]);
      *(s16x4*)&Qs[row][col4*4] = o;
    }
    #pragma unroll
    for (int i = 0; i < 2; ++i){
      int flat4 = i*256 + tid;
      if (flat4 < 384){
        int row = flat4 >> 3, col4 = flat4 & 7;
        s16x4 o = {0,0,0,0};
        if (row < 38){
          f32x4 wv = *(const f32x4*)(Wp + (long)row*DINC + kc*32 + col4*4);
          #pragma unroll
          for (int e = 0; e < 4; ++e) o[e] = bf16r(wv[e]);
        }
        *(s16x4*)&Ws[row][col4*4] = o;
      }
    }
    __syncthreads();
    #pragma unroll
    for (int rf = 0; rf < 4; ++rf){
      s16x8 af = *(const s16x8*)&Qs[wid*64 + rf*16 + lr][lk*8];
      #pragma unroll
      for (int cf = 0; cf < 3; ++cf){
        s16x8 wf = *(const s16x8*)&Ws[cf*16 + lr][lk*8];
        acc[rf][cf] = mfma16(wf, af, acc[rf][cf]);
      }
    }
    __syncthreads();
  }
  #pragma unroll
  for (int rf = 0; rf < 4; ++rf)
    #pragma unroll
    for (int cf = 0; cf < 3; ++cf){
      long row = row0 + wid*64 + rf*16 + lr;
      int n0 = cf*16 + lk*4;
      if (n0 < 38)
        *(f32x4*)(xdbl + row*40 + n0) = acc[rf][cf];
    }
}

// ---------------- depthwise causal conv1d (permuted) + SiLU, f32x4 over d ----------------
__global__ __launch_bounds__(256) void k_dwconv(const float* __restrict__ xin,
    const float* __restrict__ cw, const float* __restrict__ cb, float* __restrict__ u)
{
  long i = (long)blockIdx.x*256 + threadIdx.x;
  if (i >= 3L*BB*LTOT*48) return;
  int dq = (int)(i % 48); long t = i / 48;
  int p = (int)(t % LTOT); t /= LTOT;
  int b = (int)(t % BB); int dir = (int)(t / BB);
  int d0 = dq*4;
  f32x4 acc = *(const f32x4*)(cb + dir*DINC + d0);
  const float* wbase = cw + ((long)dir*DINC + d0)*4;
  f32x4 w0 = *(const f32x4*)(wbase);
  f32x4 w1 = *(const f32x4*)(wbase + 4);
  f32x4 w2 = *(const f32x4*)(wbase + 8);
  f32x4 w3 = *(const f32x4*)(wbase + 12);
  #pragma unroll
  for (int kk = 0; kk < 4; ++kk){
    int pp = p - 3 + kk;
    if (pp >= 0){
      int l = sigma_idx(dir, pp);
      f32x4 xv = *(const f32x4*)(xin + ((long)b*LTOT + l)*DINC + d0);
      acc[0] += xv[0] * w0[kk];
      acc[1] += xv[1] * w1[kk];
      acc[2] += xv[2] * w2[kk];
      acc[3] += xv[3] * w3[kk];
    }
  }
  #pragma unroll
  for (int e = 0; e < 4; ++e) acc[e] = silu_f(acc[e]);
  *(f32x4*)(u + (((long)dir*BB + b)*LTOT + p)*DINC + d0) = acc;
}

__global__ __launch_bounds__(256) void k_prepA(const float* __restrict__ al, float* __restrict__ A){
  int i = blockIdx.x*256 + threadIdx.x;
  if (i < 3*DINC*16) A[i] = -__expf(al[i]);
}

// ---------------- scan phase 1: wave-uniform xdbl rows via scalar loads ----------------
__global__ __launch_bounds__(192) void k_scan1(const float* __restrict__ u,
    const float* __restrict__ dt_w, const float* __restrict__ dt_b,
    const float* __restrict__ xdbl,
    const float* __restrict__ Abuf, float* __restrict__ aprod, float* __restrict__ hend)
{
  int d = threadIdx.x;
  int c  = blockIdx.x % NCHUNK;
  int bd = blockIdx.x / NCHUNK;
  int dir = bd >> 1;
  long pbase = (long)bd*LTOT + (long)c*CLEN;
  float w6[6];
  #pragma unroll
  for (int i = 0; i < 6; ++i) w6[i] = dt_w[(dir*DINC + d)*6 + i];
  float bdt = dt_b[dir*DINC + d];
  float A[16], h[16];
  #pragma unroll
  for (int s = 0; s < 16; ++s){
    A[s] = Abuf[((long)dir*DINC + d)*16 + s];
    h[s] = 0.f;
  }
  float A0 = A[0];
  bool fast = true;
  #pragma unroll
  for (int s = 1; s < 16; ++s)
    fast = fast && (fabsf(A[s] - (float)(s+1)*A0) <= 1e-4f*(float)(s+1));
  float sum_dt = 0.f;
  if (fast){
    for (int j = 0; j < CLEN; ++j){
      const float* xr = xdbl + (pbase + j)*40;
      float lu = u[(pbase + j)*DINC + d];
      float xv = bdt;
      #pragma unroll
      for (int i = 0; i < 6; ++i) xv += xr[i]*w6[i];
      float ldt = softplus_f(xv);
      sum_dt += ldt;
      float du = ldt*lu;
      float pw[16];
      pow_tree(__expf(ldt*A0), pw);
      #pragma unroll
      for (int s = 0; s < 16; ++s) h[s] = pw[s]*h[s] + du*xr[6+s];
    }
  } else {
    for (int j = 0; j < CLEN; ++j){
      const float* xr = xdbl + (pbase + j)*40;
      float lu = u[(pbase + j)*DINC + d];
      float xv = bdt;
      #pragma unroll
      for (int i = 0; i < 6; ++i) xv += xr[i]*w6[i];
      float ldt = softplus_f(xv);
      sum_dt += ldt;
      float du = ldt*lu;
      #pragma unroll
      for (int s = 0; s < 16; ++s) h[s] = __expf(ldt*A[s])*h[s] + du*xr[6+s];
    }
  }
  long oi = (((long)bd*DINC + d)*NCHUNK + c)*16;
  if (fast){
    float pw[16];
    pow_tree(__expf(A0*sum_dt), pw);
    #pragma unroll
    for (int s = 0; s < 16; ++s){ aprod[oi + s] = pw[s]; hend[oi + s] = h[s]; }
  } else {
    #pragma unroll
    for (int s = 0; s < 16; ++s){ aprod[oi + s] = __expf(A[s]*sum_dt); hend[oi + s] = h[s]; }
  }
}

// ---------------- scan phase 2 ----------------
__global__ __launch_bounds__(256) void k_scan2(float* __restrict__ aprod, const float* __restrict__ hend){
  long i = (long)blockIdx.x*256 + threadIdx.x;
  if (i >= 6L*DINC*16) return;
  int s = (int)(i & 15); long t = i >> 4;
  int d = (int)(t % DINC); int bd = (int)(t / DINC);
  long base = (((long)bd*DINC + d)*NCHUNK)*16 + s;
  float H = 0.f;
  for (int c = 0; c < NCHUNK; ++c){
    long idx = base + (long)c*16;
    float a = aprod[idx], he = hend[idx];
    aprod[idx] = H;
    H = he + a*H;
  }
}

// ---------------- scan phase 3: wave-uniform xdbl rows via scalar loads ----------------
__global__ __launch_bounds__(192) void k_scan3(const float* __restrict__ u,
    const float* __restrict__ dt_w, const float* __restrict__ dt_b,
    const float* __restrict__ xdbl,
    const float* __restrict__ Abuf, const float* __restrict__ hin,
    const float* __restrict__ Dp, const float* __restrict__ gate, float* __restrict__ qkv)
{
  int d = threadIdx.x;
  int c  = blockIdx.x % NCHUNK;
  int bd = blockIdx.x / NCHUNK;
  int dir = bd >> 1, b = bd & 1;
  long pbase = (long)bd*LTOT + (long)c*CLEN;
  float w6[6];
  #pragma unroll
  for (int i = 0; i < 6; ++i) w6[i] = dt_w[(dir*DINC + d)*6 + i];
  float bdt = dt_b[dir*DINC + d];
  float A[16], h[16];
  long oi = (((long)bd*DINC + d)*NCHUNK + c)*16;
  #pragma unroll
  for (int s = 0; s < 16; ++s){
    A[s] = Abuf[((long)dir*DINC + d)*16 + s];
    h[s] = hin[oi + s];
  }
  float A0 = A[0];
  bool fast = true;
  #pragma unroll
  for (int s = 1; s < 16; ++s)
    fast = fast && (fabsf(A[s] - (float)(s+1)*A0) <= 1e-4f*(float)(s+1));
  float Dv = Dp[dir*DINC + d];
  if (fast){
    for (int j = 0; j < CLEN; ++j){
      const float* xr = xdbl + (pbase + j)*40;
      float lu = u[(pbase + j)*DINC + d];
      float xv = bdt;
      #pragma unroll
      for (int i = 0; i < 6; ++i) xv += xr[i]*w6[i];
      float ldt = softplus_f(xv);
      float du = ldt*lu;
      float pw[16];
      pow_tree(__expf(ldt*A0), pw);
      float y = 0.f;
      #pragma unroll
      for (int s = 0; s < 16; ++s){
        h[s] = pw[s]*h[s] + du*xr[6+s];
        y += h[s]*xr[22+s];
      }
      int pl = c*CLEN + j;
      int l = sigma_idx(dir, pl);
      long li = (long)b*LTOT + l;
      qkv[(((long)dir*BB + b)*LTOT + l)*DINC + d] = (y + lu*Dv) * gate[li*DINC + d];
    }
  } else {
    for (int j = 0; j < CLEN; ++j){
      const float* xr = xdbl + (pbase + j)*40;
      float lu = u[(pbase + j)*DINC + d];
      float xv = bdt;
      #pragma unroll
      for (int i = 0; i < 6; ++i) xv += xr[i]*w6[i];
      float ldt = softplus_f(xv);
      float du = ldt*lu;
      float y = 0.f;
      #pragma unroll
      for (int s = 0; s < 16; ++s){
        h[s] = __expf(ldt*A[s])*h[s] + du*xr[6+s];
        y += h[s]*xr[22+s];
      }
      int pl = c*CLEN + j;
      int l = sigma_idx(dir, pl);
      long li = (long)b*LTOT + l;
      qkv[(((long)dir*BB + b)*LTOT + l)*DINC + d] = (y + lu*Dv) * gate[li*DINC + d];
    }
  }
}

// ---------------- QK^T via MFMA: partials per (lc,et,dtl,b) block ----------------
__global__ __launch_bounds__(256) void k_qkm(const float* __restrict__ q,
    const float* __restrict__ kkv, float* __restrict__ pb)
{
  __shared__ short Qst[64][36];
  __shared__ short Kst[64][36];
  int tid = threadIdx.x;
  int bx = blockIdx.x;
  int lc = bx % 24; int et = (bx/24) % 3; int dtl = (bx/72) % 3; int b = bx/216;
  long base = (long)b*LTOT + (long)lc*576;
  int lane = tid & 63, wid = tid >> 6;
  int lr = lane & 15, lk = lane >> 4;
  f32x4 acc[4];
  #pragma unroll
  for (int i = 0; i < 4; ++i) acc[i] = f32x4{0.f,0.f,0.f,0.f};
  for (int sc = 0; sc < 18; ++sc){
    int l0 = sc*32;
    #pragma unroll
    for (int i = 0; i < 2; ++i){
      int flat4 = i*256 + tid;
      int l = flat4 >> 4, dq = flat4 & 15;
      int d0 = dq*4;
      f32x4 qv = *(const f32x4*)(q   + (base + l0 + l)*(long)DINC + dtl*64 + d0);
      f32x4 kv = *(const f32x4*)(kkv + (base + l0 + l)*(long)DINC + et *64 + d0);
      #pragma unroll
      for (int e = 0; e < 4; ++e){
        Qst[d0+e][l] = bf16r(qv[e]);
        Kst[d0+e][l] = bf16r(kv[e]);
      }
    }
    __syncthreads();
    s16x8 kf = *(const s16x8*)&Kst[wid*16 + lr][lk*8];
    #pragma unroll
    for (int rf = 0; rf < 4; ++rf){
      s16x8 qf = *(const s16x8*)&Qst[rf*16 + lr][lk*8];
      acc[rf] = mfma16(qf, kf, acc[rf]);
    }
    __syncthreads();
  }
  float* pbb = pb + (long)bx*4096;
  #pragma unroll
  for (int rf = 0; rf < 4; ++rf)
    #pragma unroll
    for (int e = 0; e < 4; ++e)
      pbb[(rf*16 + lk*4 + e)*64 + wid*16 + lr] = acc[rf][e];
}

// ---------------- reduce qk partials over lc -> attn ----------------
__global__ __launch_bounds__(256) void k_qred(const float* __restrict__ pb,
    float* __restrict__ attn)
{
  int i4 = blockIdx.x*256 + threadIdx.x;
  if (i4 >= 18432) return;
  int i = i4*4;
  int b = i / 36864; int r = i % 36864;
  int dg = r / 192, eg = r % 192;
  int dtl = dg / 64, d = dg % 64;
  int et = eg / 64, e0 = eg % 64;
  long pbase = ((long)(24*et + 72*dtl + 216*b))*4096 + d*64 + e0;
  f32x4 s = {0.f,0.f,0.f,0.f};
  for (int lc = 0; lc < 24; ++lc){
    f32x4 v = *(const f32x4*)(pb + pbase + (long)lc*4096);
    #pragma unroll
    for (int e = 0; e < 4; ++e) s[e] += v[e];
  }
  *(f32x4*)(attn + i) = s;
}

__global__ __launch_bounds__(64) void k_softmax(float* __restrict__ attn){
  int row = blockIdx.x, tid = threadIdx.x;
  float* p = attn + (long)row*DINC;
  float v0 = p[tid], v1 = p[tid+64], v2 = p[tid+128];
  float m = fmaxf(v0, fmaxf(v1, v2));
  #pragma unroll
  for (int off = 32; off >= 1; off >>= 1) m = fmaxf(m, __shfl_xor(m, off));
  float e0 = __expf(v0-m), e1 = __expf(v1-m), e2 = __expf(v2-m);
  float s = e0 + e1 + e2;
  #pragma unroll
  for (int off = 32; off >= 1; off >>= 1) s += __shfl_xor(s, off);
  float inv = 1.f/s;
  p[tid] = e0*inv; p[tid+64] = e1*inv; p[tid+128] = e2*inv;
}

// ---------------- out_a = v @ attn^T fused with view-transpose -> inT1 bf16 ----------------
__global__ __launch_bounds__(256) void k_outa(const float* __restrict__ v,
    const float* __restrict__ attn, __hip_bfloat16* __restrict__ inT1)
{
  __shared__ short Vs[192][40];
  __shared__ short Ws[192][40];
  int tid = threadIdx.x;
  int r0 = blockIdx.x;
  int b  = blockIdx.y;
  int lane = tid & 63, wid = tid >> 6;
  int lr = lane & 15, lk = lane >> 4;
  const float* vb = v + (long)b*LTOT*DINC;
  const float* ab = attn + (long)b*DINC*DINC;
  f32x4 acc[3][12];
  #pragma unroll
  for (int i = 0; i < 3; ++i)
    #pragma unroll
    for (int j = 0; j < 12; ++j) acc[i][j] = f32x4{0.f,0.f,0.f,0.f};
  for (int kc = 0; kc < 6; ++kc){
    #pragma unroll
    for (int i = 0; i < 6; ++i){
      int flat4 = i*256 + tid;
      int row = flat4 >> 3, col4 = flat4 & 7;
      int l = r0 + 72*row;
      f32x4 vv = *(const f32x4*)(vb + (long)l*DINC + kc*32 + col4*4);
      f32x4 aa = *(const f32x4*)(ab + (long)row*DINC + kc*32 + col4*4);
      s16x4 vs, as;
      #pragma unroll
      for (int e = 0; e < 4; ++e){ vs[e] = bf16r(vv[e]); as[e] = bf16r(aa[e]); }
      *(s16x4*)&Vs[row][col4*4] = vs;
      *(s16x4*)&Ws[row][col4*4] = as;
    }
    __syncthreads();
    #pragma unroll
    for (int cf = 0; cf < 12; ++cf){
      s16x8 wf = *(const s16x8*)&Ws[cf*16 + lr][lk*8];
      #pragma unroll
      for (int c = 0; c < 3; ++c){
        s16x8 af = *(const s16x8*)&Vs[wid*48 + c*16 + lr][lk*8];
        acc[c][cf] = mfma16(af, wf, acc[c][cf]);
      }
    }
    __syncthreads();
  }
  #pragma unroll
  for (int c = 0; c < 3; ++c)
    #pragma unroll
    for (int cf = 0; cf < 12; ++cf){
      int ch0 = wid*48 + c*16 + lk*4;
      int d = cf*16 + lr;
      s16x4 o;
      #pragma unroll
      for (int e = 0; e < 4; ++e) o[e] = bf16r(acc[c][cf][e]);
      *(s16x4*)(inT1 + ((long)(b*13824 + 192*r0 + d))*192 + ch0) = o;
    }
}

// ---------------- out_m = (q+k+v) @ out_proj^T -> bf16 inT2[.][96..192) ----------------
__global__ __launch_bounds__(256) void k_outm(const float* __restrict__ qkv,
    const float* __restrict__ Wo, __hip_bfloat16* __restrict__ inT2)
{
  __shared__ short Qs[256][40];
  __shared__ short Ws[96][40];
  int tid = threadIdx.x;
  long row0 = (long)blockIdx.x * 256;
  int lane = tid & 63, wid = tid >> 6;
  int lr = lane & 15, lk = lane >> 4;
  const size_t S = (size_t)BB*LTOT*DINC;
  f32x4 acc[4][6];
  #pragma unroll
  for (int i = 0; i < 4; ++i)
    #pragma unroll
    for (int j = 0; j < 6; ++j) acc[i][j] = f32x4{0.f,0.f,0.f,0.f};
  for (int kc = 0; kc < 6; ++kc){
    #pragma unroll
    for (int i = 0; i < 8; ++i){
      int flat4 = i*256 + tid;
      int row = flat4 >> 3, col4 = flat4 & 7;
      long base = (row0 + row)*(long)DINC + kc*32 + col4*4;
      f32x4 a0 = *(const f32x4*)(qkv + base);
      f32x4 a1 = *(const f32x4*)(qkv + S + base);
      f32x4 a2 = *(const f32x4*)(qkv + 2*S + base);
      s16x4 o;
      #pragma unroll
      for (int e = 0; e < 4; ++e) o[e] = bf16r(a0[e] + a1[e] + a2[e]);
      *(s16x4*)&Qs[row][col4*4] = o;
    }
    #pragma unroll
    for (int i = 0; i < 3; ++i){
      int flat4 = i*256 + tid;
      int row = flat4 >> 3, col4 = flat4 & 7;
      f32x4 wv = *(const f32x4*)(Wo + (long)row*DINC + kc*32 + col4*4);
      s16x4 o;
      #pragma unroll
      for (int e = 0; e < 4; ++e) o[e] = bf16r(wv[e]);
      *(s16x4*)&Ws[row][col4*4] = o;
    }
    __syncthreads();
    #pragma unroll
    for (int rf = 0; rf < 4; ++rf){
      s16x8 af = *(const s16x8*)&Qs[wid*64 + rf*16 + lr][lk*8];
      #pragma unroll
      for (int cf = 0; cf < 6; ++cf){
        s16x8 wf = *(const s16x8*)&Ws[cf*16 + lr][lk*8];
        acc[rf][cf] = mfma16(wf, af, acc[rf][cf]);
      }
    }
    __syncthreads();
  }
  #pragma unroll
  for (int rf = 0; rf < 4; ++rf)
    #pragma unroll
    for (int cf = 0; cf < 6; ++cf){
      long row = row0 + wid*64 + rf*16 + lr;
      int n0 = cf*16 + lk*4;
      s16x4 o;
      #pragma unroll
      for (int e = 0; e < 4; ++e) o[e] = bf16r(acc[rf][cf][e]);
      *(s16x4*)(inT2 + row*192 + 96 + n0) = o;
    }
}

// ---------------- pack conv weights (96,192,27) f32 -> bf16 [tap][kc][oc][icl] ----------------
__global__ __launch_bounds__(256) void k_pack(const float* __restrict__ w1,
    const float* __restrict__ w2, __hip_bfloat16* __restrict__ p1, __hip_bfloat16* __restrict__ p2)
{
  int i = blockIdx.x*256 + threadIdx.x;
  if (i >= 2*497664) return;
  int which = i / 497664; int r = i % 497664;
  int icl = r & 31; int oc = (r >> 5) % 96; int kc = (r / 3072) % 6; int t = r / 18432;
  const float* w = which ? w2 : w1;
  float v = w[(long)oc*5184 + (kc*32 + icl)*27 + t];
  (which ? p2 : p1)[r] = __float2bfloat16(v);
}

// ---------------- conv3d via LDS-staged dbuf implicit GEMM, sp-tile 64 ----------------
template<int CONV>
__global__ __launch_bounds__(128, 2) void k_convm(const __hip_bfloat16* __restrict__ inT,
    const __hip_bfloat16* __restrict__ Wp, float* __restrict__ pbuf)
{
  __shared__ short As[2][64][32];
  __shared__ short Ws[2][96][32];
  int tid = threadIdx.x;
  int bx = blockIdx.x;
  int g = bx / 432; int rem = bx % 432; int b = rem / 216; int tile = rem % 216;
  int sp0 = tile * 64;
  int kd = g - 1;
  int lane = tid & 63, wid = tid >> 6;
  int lr = lane & 15, lk = lane >> 4;
  const s16x8 zer = {0,0,0,0,0,0,0,0};

  int chnk = tid & 3;
  int hh[2], wwv[2], zzv[2], spv[2];
  #pragma unroll
  for (int k = 0; k < 2; ++k){
    int sp = sp0 + (tid >> 2) + 32*k;
    spv[k] = sp; hh[k] = sp/576; wwv[k] = (sp/24)%24; zzv[k] = sp%24;
  }

  f32x4 acc[6][2];
  #pragma unroll
  for (int i = 0; i < 6; ++i)
    #pragma unroll
    for (int j = 0; j < 2; ++j) acc[i][j] = f32x4{0.f,0.f,0.f,0.f};

  s16x8 av[2], wv[3];
  {
    int dw = -1, dz = -1;
    #pragma unroll
    for (int k = 0; k < 2; ++k){
      av[k] = zer;
      bool ok = ((unsigned)(hh[k]+kd) < 24u) && ((unsigned)(wwv[k]+dw) < 24u) && ((unsigned)(zzv[k]+dz) < 24u);
      if (ok){
        int spp = spv[k] + kd*576 + dw*24 + dz;
        av[k] = *(const s16x8*)(inT + ((long)(b*13824 + spp))*192 + chnk*8);
      }
    }
    long wb = ((long)(g*9)*6)*3072;
    #pragma unroll
    for (int k = 0; k < 3; ++k)
      wv[k] = *(const s16x8*)(Wp + wb + (long)(tid + 128*k)*8);
  }
  #pragma unroll
  for (int k = 0; k < 2; ++k)
    *(s16x8*)&As[0][(tid>>2) + 32*k][chnk*8] = av[k];
  #pragma unroll
  for (int k = 0; k < 3; ++k)
    *(s16x8*)&Ws[0][(tid + 128*k) >> 2][chnk*8] = wv[k];
  __syncthreads();

  for (int s = 0; s < 54; ++s){
    int buf = s & 1;
    int sn = s + 1;
    if (sn < 54){
      int t = sn / 6, kc = sn - 6*t;
      int td3 = t / 3;
      int dw = td3 - 1, dz = t - 3*td3 - 1;
      #pragma unroll
      for (int k = 0; k < 2; ++k){
        av[k] = zer;
        bool ok = ((unsigned)(hh[k]+kd) < 24u) && ((unsigned)(wwv[k]+dw) < 24u) && ((unsigned)(zzv[k]+dz) < 24u);
        if (ok){
          int spp = spv[k] + kd*576 + dw*24 + dz;
          av[k] = *(const s16x8*)(inT + ((long)(b*13824 + spp))*192 + kc*32 + chnk*8);
        }
      }
      long wb = ((long)(g*9 + t)*6 + kc)*3072;
      #pragma unroll
      for (int k = 0; k < 3; ++k)
        wv[k] = *(const s16x8*)(Wp + wb + (long)(tid + 128*k)*8);
    }
    s16x8 bfr[2];
    #pragma unroll
    for (int c = 0; c < 2; ++c)
      bfr[c] = *(const s16x8*)&As[buf][wid*32 + c*16 + lr][lk*8];
    #pragma unroll
    for (int cf = 0; cf < 6; ++cf){
      s16x8 wf = *(const s16x8*)&Ws[buf][cf*16 + lr][lk*8];
      #pragma unroll
      for (int c = 0; c < 2; ++c){
        if (CONV == 1) acc[cf][c] = mfma16(wf, bfr[c], acc[cf][c]);
        else           acc[cf][c] = mfma16(bfr[c], wf, acc[cf][c]);
      }
    }
    if (sn < 54){
      #pragma unroll
      for (int k = 0; k < 2; ++k)
        *(s16x8*)&As[buf^1][(tid>>2) + 32*k][chnk*8] = av[k];
      #pragma unroll
      for (int k = 0; k < 3; ++k)
        *(s16x8*)&Ws[buf^1][(tid + 128*k) >> 2][chnk*8] = wv[k];
    }
    __syncthreads();
  }

  long gb = (long)(g*2 + b);
  #pragma unroll
  for (int cf = 0; cf < 6; ++cf)
    #pragma unroll
    for (int c = 0; c < 2; ++c){
      if (CONV == 1){
        int sp = sp0 + wid*32 + c*16 + lr;
        int oc0 = cf*16 + lk*4;
        *reinterpret_cast<f32x4*>(pbuf + (gb*13824 + sp)*96 + oc0) = acc[cf][c];
      } else {
        int oc = cf*16 + lr;
        int spr = sp0 + wid*32 + c*16 + lk*4;
        *reinterpret_cast<f32x4*>(pbuf + (gb*96 + oc)*13824 + spr) = acc[cf][c];
      }
    }
}

// ---------------- reduce conv1 partials + bias -> bf16 inT2[.][0..96), f32x4 ----------------
__global__ __launch_bounds__(256) void k_red1(const float* __restrict__ pbuf,
    const float* __restrict__ bias, __hip_bfloat16* __restrict__ inT2)
{
  int i4 = blockIdx.x*256 + threadIdx.x;
  if (i4 >= 663552) return;
  int i = i4*4;
  int oc0 = i % 96;
  long row = i / 96;
  f32x4 v0 = *(const f32x4*)(pbuf + i);
  f32x4 v1 = *(const f32x4*)(pbuf + 2654208 + i);
  f32x4 v2 = *(const f32x4*)(pbuf + 2*2654208 + i);
  f32x4 bv = *(const f32x4*)(bias + oc0);
  s16x4 o;
  #pragma unroll
  for (int e = 0; e < 4; ++e) o[e] = bf16r(v0[e] + v1[e] + v2[e] + bv[e]);
  *(s16x4*)(inT2 + row*192 + oc0) = o;
}

// ---------------- reduce conv2 partials + bias + x -> d_out, f32x4 ----------------
__global__ __launch_bounds__(256) void k_red2(const float* __restrict__ pbuf,
    const float* __restrict__ bias, const float* __restrict__ x, float* __restrict__ out)
{
  int i4 = blockIdx.x*256 + threadIdx.x;
  if (i4 >= 663552) return;
  int i = i4*4;
  int oc = (i / 13824) % 96;
  f32x4 v0 = *(const f32x4*)(pbuf + i);
  f32x4 v1 = *(const f32x4*)(pbuf + 2654208 + i);
  f32x4 v2 = *(const f32x4*)(pbuf + 2*2654208 + i);
  f32x4 xv = *(const f32x4*)(x + i);
  f32x4 o;
  float bv = bias[oc];
  #pragma unroll
  for (int e = 0; e < 4; ++e) o[e] = v0[e] + v1[e] + v2[e] + bv + xv[e];
  *(f32x4*)(out + i) = o;
}

extern "C" void kernel_launch(void* const* d_in, const int* in_sizes, int n_in,
                              void* d_out, int out_size, void* d_ws, size_t ws_size,
                              hipStream_t stream)
{
  const float* x          = (const float*)d_in[0];
  const float* ln_g       = (const float*)d_in[1];
  const float* ln_b       = (const float*)d_in[2];
  const float* in_proj_w  = (const float*)d_in[3];
  const float* conv_w     = (const float*)d_in[4];
  const float* conv_b     = (const float*)d_in[5];
  const float* xproj_w    = (const float*)d_in[6];
  const float* dt_w       = (const float*)d_in[7];
  const float* dt_b       = (const float*)d_in[8];
  const float* A_log      = (const float*)d_in[9];
  const float* Dp         = (const float*)d_in[10];
  const float* out_proj_w = (const float*)d_in[11];
  const float* f1_w       = (const float*)d_in[12];
  const float* f1_b       = (const float*)d_in[13];
  const float* f2_w       = (const float*)d_in[14];
  const float* f2_b       = (const float*)d_in[15];
  float* out = (float*)d_out;

  const size_t BL = (size_t)BB*LTOT;
  const size_t S  = BL*DINC;

  void* wsp = nullptr;
  (void)hipGetSymbolAddress(&wsp, HIP_SYMBOL(g_ws));
  float* ws = (float*)wsp;
  size_t off = 0;
  auto alloc = [&](size_t n){ float* p = ws + off; off += n; return p; };
  float* xnorm = alloc(BL*C0);
  float* xin   = alloc(S);
  float* gate  = alloc(S);
  float* u     = alloc(3*S);
  float* xdbl  = alloc(3*BL*40);
  float* qkv   = alloc(3*S);
  float* Abuf  = alloc(3*DINC*16);
  float* aprod = alloc((size_t)6*DINC*16*NCHUNK);
  float* hend  = alloc((size_t)6*DINC*16*NCHUNK);
  float* attn  = alloc((size_t)BB*DINC*DINC);
  float* pbuf  = alloc((size_t)3*2654208);
  __hip_bfloat16* inT1 = (__hip_bfloat16*)alloc(2654208);
  __hip_bfloat16* inT2 = (__hip_bfloat16*)alloc(2654208);
  __hip_bfloat16* Wp1  = (__hip_bfloat16*)alloc(248832);
  __hip_bfloat16* Wp2  = (__hip_bfloat16*)alloc(248832);

  // 0) pack conv weights to bf16
  k_pack<<<3888, 256, 0, stream>>>(f1_w, f2_w, Wp1, Wp2);
  // 1) layernorm + transpose
  k_ln<<<108, 256, 0, stream>>>(x, ln_g, ln_b, xnorm);
  // 2) in_proj MFMA -> xin + silu gate
  k_inproj<<<dim3(108, 4), 256, 0, stream>>>(xnorm, in_proj_w, xin, gate);
  // 3) depthwise causal conv + silu
  k_dwconv<<<15552, 256, 0, stream>>>(xin, conv_w, conv_b, u);
  // 4) xproj MFMA -> xdbl (stride 40)
  k_xproj<<<324, 256, 0, stream>>>(u, xproj_w, xdbl);
  // 5) A = -exp(A_log)
  k_prepA<<<36, 256, 0, stream>>>(A_log, Abuf);
  // 6) chunked selective scan (192-thread blocks, 16 states/thread)
  k_scan1<<<6*NCHUNK, 192, 0, stream>>>(u, dt_w, dt_b, xdbl, Abuf, aprod, hend);
  k_scan2<<<72, 256, 0, stream>>>(aprod, hend);
  k_scan3<<<6*NCHUNK, 192, 0, stream>>>(u, dt_w, dt_b, xdbl, Abuf, aprod, Dp, gate, qkv);
  // 7) attention matrix (MFMA + partial reduce) + softmax
  k_qkm<<<432, 256, 0, stream>>>(qkv, qkv + S, pbuf);
  k_qred<<<72, 256, 0, stream>>>(pbuf, attn);
  k_softmax<<<BB*DINC, 64, 0, stream>>>(attn);
  // 8) out_a MFMA + fused transpose -> inT1 bf16
  k_outa<<<dim3(72, 2), 256, 0, stream>>>(qkv + 2*S, attn, inT1);
  // 9) out_m MFMA -> bf16 inT2[.][96..192)
  k_outm<<<108, 256, 0, stream>>>(qkv, out_proj_w, inT2);
  // 10) conv3d #1 (sp-tile 64, grid 1296) + reduce -> inT2[.][0..96)
  k_convm<1><<<1296, 128, 0, stream>>>(inT1, Wp1, pbuf);
  k_red1<<<2592, 256, 0, stream>>>(pbuf, f1_b, inT2);
  // 11) conv3d #2 + reduce + bias + x -> d_out
  k_convm<2><<<1296, 128, 0, stream>>>(inT2, Wp2, pbuf);
  k_red2<<<2592, 256, 0, stream>>>(pbuf, f2_b, x, out);
}